// Round 1
// baseline (682.808 us; speedup 1.0000x reference)
//
#include <hip/hip_runtime.h>
#include <stdint.h>

#define N_TOK 7200
#define N_PAD 7232      // old fp32 z padding (113*64)
#define N_PAD_A 7296    // 57*128, dpass A-tile row padding
#define K_CODE 8912
#define K_PAD 8960      // 140*64 = 70*128
#define N_KT 140        // 64-col half-tiles (combine granularity, unchanged)
#define NKT128 70       // 128-col dpass tiles
#define NMT128 57       // 128-row dpass tiles
#define MID 256
#define C_DIM 768
#define INV_TEMP (1.0f/0.07f)
#define INV_ETEMP 100.0f
#define MARGIN 0.02f
#define CAND_CAP 64
#define EPS_N 1e-12f

typedef __attribute__((ext_vector_type(8))) short short8;   // 8 bf16 (4 VGPRs)
typedef __attribute__((ext_vector_type(4))) float f32x4;

__device__ __forceinline__ unsigned short f2bf(float f) {
    unsigned u = __float_as_uint(f);
    u += 0x7fffu + ((u >> 16) & 1u);   // round-to-nearest-even
    return (unsigned short)(u >> 16);
}
__device__ __forceinline__ float bf2f(unsigned short h) {
    return __uint_as_float(((unsigned)h) << 16);
}

// async global->LDS, 16B per lane; LDS dest = wave-uniform base + lane*16
__device__ __forceinline__ void gload16(const void* g, void* l) {
    __builtin_amdgcn_global_load_lds(
        (const __attribute__((address_space(1))) unsigned int*)g,
        (__attribute__((address_space(3))) unsigned int*)l,
        16, 0, 0);
}

// ---------------- init: zero accumulators + zero bf16 pad rows --------------
__global__ void k_init(float* ap_acc, int* used, float* acc4, int* ccnt,
                       unsigned short* zn_h, unsigned short* en_h) {
    int i = blockIdx.x * 256 + threadIdx.x;     // 0..8959
    if (i < K_CODE) { ap_acc[i] = 0.f; used[i] = 0; }
    if (i < N_TOK) ccnt[i] = 0;
    if (i < 4) acc4[i] = 0.f;
    // zn_h rows [N_TOK, N_PAD_A) = 96*256 elems; en_h rows [K_CODE, K_PAD) = 48*256
    for (int j = i; j < (N_PAD_A - N_TOK) * MID; j += 8960) zn_h[(size_t)N_TOK * MID + j] = 0;
    for (int j = i; j < (K_PAD - K_CODE) * MID; j += 8960) en_h[(size_t)K_CODE * MID + j] = 0;
}

// ---------------- W_down -> transposed bf16 hi/lo splits ---------------------
__global__ void k_wsplit(const float* __restrict__ W,
                         unsigned short* __restrict__ wt_h,
                         unsigned short* __restrict__ wt_l) {
    int i = blockIdx.x * 256 + threadIdx.x;
    if (i >= C_DIM * MID) return;
    int c = i / MID, t = i % MID;
    float v = W[i];
    unsigned short h = f2bf(v);
    unsigned short l = f2bf(v - bf2f(h));
    wt_h[t * C_DIM + c] = h;
    wt_l[t * C_DIM + c] = l;
}

// ---------------- embedding l2norm -> en (f32) + en_h (bf16) ----------------
__global__ void k_ennorm(const float* __restrict__ emb,
                         float* __restrict__ en,
                         unsigned short* __restrict__ en_h) {
    int n = blockIdx.x, t = threadIdx.x;
    float v = emb[n * MID + t];
    __shared__ float sb[256];
    sb[t] = v * v; __syncthreads();
    for (int s = 128; s > 0; s >>= 1) { if (t < s) sb[t] += sb[t + s]; __syncthreads(); }
    float nn = sqrtf(sb[0]);
    float o = v / fmaxf(nn, EPS_N);
    en[n * MID + t] = o;
    en_h[n * MID + t] = f2bf(o);
}

// ---------------- z = x @ W_down via bf16x3 MFMA (fp32-quality) -------------
__global__ __launch_bounds__(256) void k_zgemm(const float* __restrict__ x,
                                               const unsigned short* __restrict__ wt_h,
                                               const unsigned short* __restrict__ wt_l,
                                               float* __restrict__ zbuf) {
    __shared__ unsigned short ls[4 * 64 * 72];
    unsigned short* xh = ls;
    unsigned short* xl = ls + 64 * 72;
    unsigned short* wh = ls + 2 * 64 * 72;
    unsigned short* wl = ls + 3 * 64 * 72;
    int tid = threadIdx.x;
    int m0 = blockIdx.y * 64;
    int t0 = blockIdx.x * 64;
    int lane = tid & 63, wv = tid >> 6;
    int quad = lane >> 4, l15 = lane & 15;
    int mrow0 = (wv >> 1) * 32, ncol0 = (wv & 1) * 32;
    f32x4 acc[2][2] = {};

    for (int ch = 0; ch < 12; ch++) {
        int c0 = ch * 64;
        for (int it = 0; it < 4; it++) {
            int r = it * 16 + (tid >> 4);
            int cq = tid & 15;
            float4 v = make_float4(0.f, 0.f, 0.f, 0.f);
            int gr = m0 + r;
            if (gr < N_TOK) v = ((const float4*)x)[(size_t)gr * (C_DIM / 4) + (c0 >> 2) + cq];
            unsigned short h0 = f2bf(v.x), h1 = f2bf(v.y), h2 = f2bf(v.z), h3 = f2bf(v.w);
            ushort4 hh = make_ushort4(h0, h1, h2, h3);
            ushort4 ll = make_ushort4(f2bf(v.x - bf2f(h0)), f2bf(v.y - bf2f(h1)),
                                      f2bf(v.z - bf2f(h2)), f2bf(v.w - bf2f(h3)));
            *((ushort4*)&xh[r * 72 + cq * 4]) = hh;
            *((ushort4*)&xl[r * 72 + cq * 4]) = ll;
        }
        for (int it = 0; it < 2; it++) {
            int r = it * 32 + (tid >> 3);
            int cq = tid & 7;
            uint4 vh = ((const uint4*)wt_h)[(size_t)(t0 + r) * (C_DIM / 8) + (c0 >> 3) + cq];
            uint4 vl = ((const uint4*)wt_l)[(size_t)(t0 + r) * (C_DIM / 8) + (c0 >> 3) + cq];
            *((uint4*)&wh[r * 72 + cq * 8]) = vh;
            *((uint4*)&wl[r * 72 + cq * 8]) = vl;
        }
        __syncthreads();
        for (int ks = 0; ks < 2; ks++) {
            int co = ks * 32 + quad * 8;
            short8 ah0 = *((const short8*)&xh[(mrow0 + l15) * 72 + co]);
            short8 ah1 = *((const short8*)&xh[(mrow0 + 16 + l15) * 72 + co]);
            short8 al0 = *((const short8*)&xl[(mrow0 + l15) * 72 + co]);
            short8 al1 = *((const short8*)&xl[(mrow0 + 16 + l15) * 72 + co]);
            short8 bh0 = *((const short8*)&wh[(ncol0 + l15) * 72 + co]);
            short8 bh1 = *((const short8*)&wh[(ncol0 + 16 + l15) * 72 + co]);
            short8 bl0 = *((const short8*)&wl[(ncol0 + l15) * 72 + co]);
            short8 bl1 = *((const short8*)&wl[(ncol0 + 16 + l15) * 72 + co]);
            acc[0][0] = __builtin_amdgcn_mfma_f32_16x16x32_bf16(ah0, bh0, acc[0][0], 0, 0, 0);
            acc[0][1] = __builtin_amdgcn_mfma_f32_16x16x32_bf16(ah0, bh1, acc[0][1], 0, 0, 0);
            acc[1][0] = __builtin_amdgcn_mfma_f32_16x16x32_bf16(ah1, bh0, acc[1][0], 0, 0, 0);
            acc[1][1] = __builtin_amdgcn_mfma_f32_16x16x32_bf16(ah1, bh1, acc[1][1], 0, 0, 0);
            acc[0][0] = __builtin_amdgcn_mfma_f32_16x16x32_bf16(ah0, bl0, acc[0][0], 0, 0, 0);
            acc[0][1] = __builtin_amdgcn_mfma_f32_16x16x32_bf16(ah0, bl1, acc[0][1], 0, 0, 0);
            acc[1][0] = __builtin_amdgcn_mfma_f32_16x16x32_bf16(ah1, bl0, acc[1][0], 0, 0, 0);
            acc[1][1] = __builtin_amdgcn_mfma_f32_16x16x32_bf16(ah1, bl1, acc[1][1], 0, 0, 0);
            acc[0][0] = __builtin_amdgcn_mfma_f32_16x16x32_bf16(al0, bh0, acc[0][0], 0, 0, 0);
            acc[0][1] = __builtin_amdgcn_mfma_f32_16x16x32_bf16(al0, bh1, acc[0][1], 0, 0, 0);
            acc[1][0] = __builtin_amdgcn_mfma_f32_16x16x32_bf16(al1, bh0, acc[1][0], 0, 0, 0);
            acc[1][1] = __builtin_amdgcn_mfma_f32_16x16x32_bf16(al1, bh1, acc[1][1], 0, 0, 0);
        }
        __syncthreads();
    }
    for (int i = 0; i < 2; i++)
        for (int j = 0; j < 2; j++)
            for (int r = 0; r < 4; r++) {
                int gr = m0 + mrow0 + i * 16 + quad * 4 + r;
                int gc = t0 + ncol0 + j * 16 + l15;
                if (gr < N_TOK) zbuf[(size_t)gr * MID + gc] = acc[i][j][r];
            }
}

// ---------------- z + b -> l2norm -> zn (in place) + zn_h -------------------
__global__ void k_znorm(float* __restrict__ zbuf, const float* __restrict__ b_down,
                        unsigned short* __restrict__ zn_h) {
    int n = blockIdx.x, t = threadIdx.x;
    float v = zbuf[(size_t)n * MID + t] + b_down[t];
    __shared__ float sb[256];
    sb[t] = v * v; __syncthreads();
    for (int s = 128; s > 0; s >>= 1) { if (t < s) sb[t] += sb[t + s]; __syncthreads(); }
    float nn = sqrtf(sb[0]);
    float o = v / fmaxf(nn, EPS_N);
    zbuf[(size_t)n * MID + t] = o;
    zn_h[(size_t)n * MID + t] = f2bf(o);
}

// ---------------- d-GEMM, m97-style 128x128 tile, global_load_lds staging ---
// LDS layout: A[128 rows][64 cols] bf16, linear rows (128B/row), column bytes
// XOR-swizzled by ((row&7)<<4) via pre-swizzled GLOBAL source (rule 21) so
// global_load_lds keeps a linear dest and ds_read_b128 is conflict-free.
// PASS 1: per-(row, 64-col half) partials {min, st, s1, s2} -> part4 (140 halves)
// PASS 2: probs -> out1, avg_probs column sums, element-level candidates
template<int PASS>
__global__ __launch_bounds__(256) void k_dpass(const unsigned short* __restrict__ zn_h,
                                               const unsigned short* __restrict__ en_h,
                                               float4* __restrict__ part4,
                                               const float* __restrict__ rs_m,
                                               const float* __restrict__ rs_ist,
                                               const float* __restrict__ rs_is1,
                                               float* __restrict__ ap_acc,
                                               float* __restrict__ out1,
                                               int* __restrict__ ccnt,
                                               int* __restrict__ cand) {
    __shared__ __align__(16) unsigned short lds[2 * 128 * 64];   // 32 KiB
    unsigned short* lA = lds;
    unsigned short* lB = lds + 128 * 64;
    int tid = threadIdx.x;
    int kt = blockIdx.x, mt = blockIdx.y;
    int m0 = mt * 128, k0 = kt * 128;
    int lane = tid & 63, wv = tid >> 6;
    int quad = lane >> 4, l15 = lane & 15;
    int wr = wv >> 1, wc = wv & 1;          // wave sub-tile: rows wr*64, cols wc*64
    f32x4 acc[4][4] = {};

    // staging coords: LDS linear offset L = it*4096 + tid*16 -> row, col-byte
    int sr = tid >> 3;                      // row within 32-row group
    int scb = (tid & 7) * 16;               // dest col byte (0..112)

    for (int step = 0; step < 4; step++) {
        int cB = step * 128;                // global byte offset within row (64 cols)
        #pragma unroll
        for (int it = 0; it < 4; it++) {
            int r = it * 32 + sr;
            int srcb = scb ^ ((r & 7) << 4);     // pre-swizzled source column
            const char* gA = (const char*)zn_h + (size_t)(m0 + r) * 512 + cB + srcb;
            const char* gB = (const char*)en_h + (size_t)(k0 + r) * 512 + cB + srcb;
            gload16(gA, (char*)lA + it * 4096 + wv * 1024);   // wave-uniform LDS base
            gload16(gB, (char*)lB + it * 4096 + wv * 1024);
        }
        __syncthreads();    // compiler drains vmcnt(0) before s_barrier
        #pragma unroll
        for (int ks = 0; ks < 2; ks++) {
            short8 a[4], b[4];
            #pragma unroll
            for (int i = 0; i < 4; i++) {
                int ra = wr * 64 + i * 16 + l15;
                int ca = (ks * 64 + quad * 16) ^ ((ra & 7) << 4);
                a[i] = *(const short8*)((const char*)lA + ra * 128 + ca);
                int rb = wc * 64 + i * 16 + l15;
                int cb2 = (ks * 64 + quad * 16) ^ ((rb & 7) << 4);
                b[i] = *(const short8*)((const char*)lB + rb * 128 + cb2);
            }
            #pragma unroll
            for (int i = 0; i < 4; i++)
                #pragma unroll
                for (int j = 0; j < 4; j++)
                    acc[i][j] = __builtin_amdgcn_mfma_f32_16x16x32_bf16(a[i], b[j], acc[i][j], 0, 0, 0);
        }
        __syncthreads();
    }

    // C layout per fragment: row = quad*4 + r, col = l15 (verified m89/m91)
    if (PASS == 1) {
        int kth = kt * 2 + wc;              // 64-col half index, 0..139
        #pragma unroll
        for (int i = 0; i < 4; i++) {
            #pragma unroll
            for (int r = 0; r < 4; r++) {
                float dv[4]; float vmin = 1e30f;
                #pragma unroll
                for (int j = 0; j < 4; j++) {
                    int gc = k0 + wc * 64 + j * 16 + l15;
                    float d = 2.f - 2.f * acc[i][j][r];
                    dv[j] = (gc < K_CODE) ? d : 1e30f;
                    vmin = fminf(vmin, dv[j]);
                }
                vmin = fminf(vmin, __shfl_xor(vmin, 1));
                vmin = fminf(vmin, __shfl_xor(vmin, 2));
                vmin = fminf(vmin, __shfl_xor(vmin, 4));
                vmin = fminf(vmin, __shfl_xor(vmin, 8));
                float st = 0.f, s1 = 0.f, s2 = 0.f;
                #pragma unroll
                for (int j = 0; j < 4; j++) {
                    float dd = vmin - dv[j];         // <=0; masked: -1e30 -> exp=0
                    st += __expf(dd * INV_TEMP);
                    float te = dd * INV_ETEMP;
                    float e = __expf(te);
                    s1 += e; s2 += e * te;
                }
                st += __shfl_xor(st, 1); st += __shfl_xor(st, 2);
                st += __shfl_xor(st, 4); st += __shfl_xor(st, 8);
                s1 += __shfl_xor(s1, 1); s1 += __shfl_xor(s1, 2);
                s1 += __shfl_xor(s1, 4); s1 += __shfl_xor(s1, 8);
                s2 += __shfl_xor(s2, 1); s2 += __shfl_xor(s2, 2);
                s2 += __shfl_xor(s2, 4); s2 += __shfl_xor(s2, 8);
                if (l15 == 0) {
                    int gr = m0 + wr * 64 + i * 16 + quad * 4 + r;
                    if (gr < N_TOK) part4[(size_t)gr * N_KT + kth] = make_float4(vmin, st, s1, s2);
                }
            }
        }
    } else {
        // LDS reuse after final barrier: row stats + column accumulator
        float* lm = (float*)lds;            // 128
        float* lt_ = lm + 128;              // 128
        float* l1_ = lt_ + 128;             // 128
        float* colacc = l1_ + 128;          // 2*128
        if (tid < 128) {
            int gr = m0 + tid;
            bool ok = gr < N_TOK;
            lm[tid]  = ok ? rs_m[gr]   : 0.f;
            lt_[tid] = ok ? rs_ist[gr] : 0.f;
            l1_[tid] = ok ? rs_is1[gr] : 0.f;
        }
        __syncthreads();
        float ce[4] = {0.f, 0.f, 0.f, 0.f};
        #pragma unroll
        for (int i = 0; i < 4; i++) {
            #pragma unroll
            for (int r = 0; r < 4; r++) {
                int lr = wr * 64 + i * 16 + quad * 4 + r;
                int gr = m0 + lr;
                float m_ = lm[lr], t_ = lt_[lr], i1 = l1_[lr];
                bool okr = gr < N_TOK;
                float thr = m_ + MARGIN;
                #pragma unroll
                for (int j = 0; j < 4; j++) {
                    int gc = k0 + wc * 64 + j * 16 + l15;
                    if (okr && gc < K_CODE) {
                        float d = 2.f - 2.f * acc[i][j][r];
                        ce[j] += __expf((m_ - d) * INV_ETEMP) * i1;
                        float p = __expf((m_ - d) * INV_TEMP) * t_;
                        out1[(size_t)gr * K_CODE + gc] = p;
                        if (d <= thr) {
                            int pd = atomicAdd(&ccnt[gr], 1);
                            if (pd < CAND_CAP) cand[gr * CAND_CAP + pd] = gc;
                        }
                    }
                }
            }
        }
        #pragma unroll
        for (int j = 0; j < 4; j++) {
            ce[j] += __shfl_xor(ce[j], 16);
            ce[j] += __shfl_xor(ce[j], 32);
        }
        if (quad == 0) {
            #pragma unroll
            for (int j = 0; j < 4; j++)
                colacc[wr * 128 + wc * 64 + j * 16 + l15] = ce[j];
        }
        __syncthreads();
        if (tid < 128) {
            int gc = k0 + tid;
            if (gc < K_CODE) atomicAdd(&ap_acc[gc], colacc[tid] + colacc[128 + tid]);
        }
    }
}

// ---------------- combine 140 tile-partials per row -------------------------
__global__ void k_combine(const float4* __restrict__ part4,
                          float* __restrict__ rs_m, float* __restrict__ rs_ist,
                          float* __restrict__ rs_is1,
                          float* __restrict__ acc4) {
    int sub = threadIdx.x >> 6;
    int row = blockIdx.x * 4 + sub;
    int l = threadIdx.x & 63;
    float4 pv[3];
    float m = 1e30f;
    #pragma unroll
    for (int c = 0; c < 3; c++) {
        int t = l + c * 64;
        pv[c] = (t < N_KT) ? part4[(size_t)row * N_KT + t] : make_float4(1e30f, 0.f, 0.f, 0.f);
        m = fminf(m, pv[c].x);
    }
    #pragma unroll
    for (int s = 1; s < 64; s <<= 1) m = fminf(m, __shfl_xor(m, s));
    float st = 0.f, s1 = 0.f, s2 = 0.f;
    #pragma unroll
    for (int c = 0; c < 3; c++) {
        float mb = pv[c].x;
        int t = l + c * 64;
        if (t < N_KT && mb < 1e29f) {
            float dT = (m - mb) * INV_TEMP;
            st += __expf(dT) * pv[c].y;
            float dE = (m - mb) * INV_ETEMP;
            float e = __expf(dE);
            s1 += e * pv[c].z;
            s2 += e * (pv[c].w + dE * pv[c].z);
        }
    }
    #pragma unroll
    for (int s = 1; s < 64; s <<= 1) {
        st += __shfl_xor(st, s);
        s1 += __shfl_xor(s1, s);
        s2 += __shfl_xor(s2, s);
    }
    if (l == 0) {
        rs_m[row] = m;
        rs_ist[row] = 1.f / st;
        rs_is1[row] = 1.f / s1;
        atomicAdd(&acc4[1], s2 / s1 - __logf(s1));
    }
}

// ---------------- exact fp32 argmin over element candidates -----------------
__global__ void k_refine(const float* __restrict__ zn, const float* __restrict__ en,
                         const int* __restrict__ ccnt, const int* __restrict__ cand,
                         int* __restrict__ idxb, int* __restrict__ used,
                         float* __restrict__ acc4) {
    int n = blockIdx.x * 4 + (threadIdx.x >> 6);
    int lane = threadIdx.x & 63;
    if (n >= N_TOK) return;
    int cnt = ccnt[n];
    if (cnt > CAND_CAP) cnt = CAND_CAP;
    float4 a = ((const float4*)(zn + (size_t)n * MID))[lane];
    float best = 1e30f; int bj = K_CODE;
    for (int c = 0; c < cnt; c++) {
        int code = cand[n * CAND_CAP + c];
        float4 b = ((const float4*)(en + (size_t)code * MID))[lane];
        float s = a.x * b.x + a.y * b.y + a.z * b.z + a.w * b.w;
        #pragma unroll
        for (int off = 1; off < 64; off <<= 1) s += __shfl_xor(s, off);
        float dist = 2.f - 2.f * s;
        if (dist < best || (dist == best && code < bj)) { best = dist; bj = code; }
    }
    float4 b = ((const float4*)(en + (size_t)bj * MID))[lane];
    float dx = b.x - a.x, dy = b.y - a.y, dz = b.z - a.z, dw = b.w - a.w;
    float sq = dx * dx + dy * dy + dz * dz + dw * dw;
    #pragma unroll
    for (int off = 32; off > 0; off >>= 1) sq += __shfl_down(sq, off);
    if (lane == 0) {
        idxb[n] = bj;
        used[bj] = 1;
        atomicAdd(&acc4[0], sq);
    }
}

// ---------------- output 0: z_q_ste = en[idx] -------------------------------
__global__ void k_out0(const float* __restrict__ en, const int* __restrict__ idxb,
                       float* __restrict__ out0) {
    int n = blockIdx.x, t = threadIdx.x;
    int j = idxb[n];
    out0[(size_t)n * MID + t] = en[(size_t)j * MID + t];
}

// ---------------- final scalars ---------------------------------------------
__global__ void k_scal(const int* __restrict__ used, const float* __restrict__ ap_acc,
                       const float* __restrict__ acc4, float* __restrict__ outs) {
    int t = threadIdx.x;
    float uSum = 0.f, aeSum = 0.f;
    for (int k = t; k < K_CODE; k += 256) {
        uSum += (float)used[k];
        float ap = ap_acc[k] * (1.0f / (float)N_TOK);
        aeSum += ap * __logf(ap + 1e-5f);
    }
    __shared__ float sb[256];
    sb[t] = uSum; __syncthreads();
    for (int s = 128; s > 0; s >>= 1) { if (t < s) sb[t] += sb[t + s]; __syncthreads(); }
    uSum = sb[0];
    __syncthreads(); sb[t] = aeSum; __syncthreads();
    for (int s = 128; s > 0; s >>= 1) { if (t < s) sb[t] += sb[t + s]; __syncthreads(); }
    aeSum = sb[0];
    if (t == 0) {
        outs[0] = uSum / (float)K_CODE;
        float vq = acc4[0] / (float)((size_t)N_TOK * MID);
        outs[1] = vq;
        outs[2] = vq;
        outs[3] = -(acc4[1] / (float)N_TOK) + aeSum;
    }
}

extern "C" void kernel_launch(void* const* d_in, const int* in_sizes, int n_in,
                              void* d_out, int out_size, void* d_ws, size_t ws_size,
                              hipStream_t stream) {
    const float* x   = (const float*)d_in[0];
    const float* W   = (const float*)d_in[1];
    const float* b   = (const float*)d_in[2];
    const float* emb = (const float*)d_in[3];

    float* out  = (float*)d_out;
    float* out0 = out;                                                  // [7200*256]
    float* out1 = out + (size_t)N_TOK * MID;                            // probs
    float* outs = out + (size_t)N_TOK * MID + (size_t)N_TOK * K_CODE;   // 4 scalars

    char* w = (char*)d_ws;
    size_t off = 0;
    auto carve = [&](size_t bytes) { void* p = w + off; off += (bytes + 255) & ~(size_t)255; return p; };
    float*          zn    = (float*)         carve((size_t)N_PAD * MID * 4);
    float*          en    = (float*)         carve((size_t)K_PAD * MID * 4);
    unsigned short* zn_h  = (unsigned short*)carve((size_t)N_PAD_A * MID * 2);
    unsigned short* en_h  = (unsigned short*)carve((size_t)K_PAD * MID * 2);
    unsigned short* wt_h  = (unsigned short*)carve((size_t)MID * C_DIM * 2);
    unsigned short* wt_l  = (unsigned short*)carve((size_t)MID * C_DIM * 2);
    float4*         part4 = (float4*)        carve((size_t)N_TOK * N_KT * 16);
    float*          rs_m  = (float*)         carve((size_t)N_TOK * 4);
    float*          rs_ist= (float*)         carve((size_t)N_TOK * 4);
    float*          rs_is1= (float*)         carve((size_t)N_TOK * 4);
    int*            ccnt  = (int*)           carve((size_t)N_TOK * 4);
    int*            cand  = (int*)           carve((size_t)N_TOK * CAND_CAP * 4);
    int*            idxb  = (int*)           carve((size_t)N_TOK * 4);
    float*          ap_acc= (float*)         carve((size_t)K_CODE * 4);
    int*            used  = (int*)           carve((size_t)K_CODE * 4);
    float*          acc4  = (float*)         carve(16);
    (void)ws_size; (void)in_sizes; (void)n_in; (void)out_size;

    k_init   <<<35, 256, 0, stream>>>(ap_acc, used, acc4, ccnt, zn_h, en_h);
    k_wsplit <<<(C_DIM * MID + 255) / 256, 256, 0, stream>>>(W, wt_h, wt_l);
    k_ennorm <<<K_CODE, 256, 0, stream>>>(emb, en, en_h);
    k_zgemm  <<<dim3(4, 113), 256, 0, stream>>>(x, wt_h, wt_l, zn);
    k_znorm  <<<N_TOK, 256, 0, stream>>>(zn, b, zn_h);
    k_dpass<1><<<dim3(NKT128, NMT128), 256, 0, stream>>>(zn_h, en_h, part4, rs_m, rs_ist, rs_is1, ap_acc, out1, ccnt, cand);
    k_combine<<<N_TOK / 4, 256, 0, stream>>>(part4, rs_m, rs_ist, rs_is1, acc4);
    k_dpass<2><<<dim3(NKT128, NMT128), 256, 0, stream>>>(zn_h, en_h, part4, rs_m, rs_ist, rs_is1, ap_acc, out1, ccnt, cand);
    k_refine <<<N_TOK / 4, 256, 0, stream>>>(zn, en, ccnt, cand, idxb, used, acc4);
    k_out0   <<<N_TOK, 256, 0, stream>>>(en, idxb, out0);
    k_scal   <<<1, 256, 0, stream>>>(used, ap_acc, acc4, outs);
}